// Round 6
// baseline (425.733 us; speedup 1.0000x reference)
//
#include <hip/hip_runtime.h>
#include <math.h>

#define B_  4
#define C_  256
#define C8_ 32
#define N_  4096
#define NT64_ 64         // 4096 / 64 m-tiles in pv_k

typedef __attribute__((ext_vector_type(8))) short          bf16x8;
typedef __attribute__((ext_vector_type(8))) unsigned short us8;
typedef __attribute__((ext_vector_type(4))) unsigned short us4;
typedef __attribute__((ext_vector_type(4))) float          f32x4;
typedef __attribute__((ext_vector_type(4))) unsigned       u32x4;

__device__ inline unsigned short f2bf(float f) {
    unsigned u = __float_as_uint(f);
    u += 0x7FFFu + ((u >> 16) & 1u);        // RNE
    return (unsigned short)(u >> 16);
}
__device__ inline void splitbf(float v, unsigned short& h, unsigned short& l) {
    unsigned short hh = f2bf(v);
    float hf = __uint_as_float((unsigned)hh << 16);
    h = hh; l = f2bf(v - hf);
}
__device__ inline unsigned packbf(float v) {     // hi | lo<<16
    unsigned short h, l; splitbf(v, h, l);
    return (unsigned)h | ((unsigned)l << 16);
}
__device__ inline bf16x8 asb(us8 v) { return __builtin_bit_cast(bf16x8, v); }

// ---------------------------------------------------------------------------
// proj<0>: [Wq;Wk] GEMM.  64 m x 64 cc per block, 256 thr / 4 waves.
//   qt[b][n][32] f32, kt[b][m][32] f32 (both row-major per position).
// proj<1>: Wv GEMM.  64 m x 128 cc per block.  vtc[b][s*256+cc][m] bf16.
// X staged as packed hi|lo u32 plane (one b32 read per A-frag element).
// ---------------------------------------------------------------------------
template<int MODE>
__global__ __launch_bounds__(256, 4) void proj_k(
    const float* __restrict__ Xa, const float* __restrict__ Xb,
    const float* __restrict__ Wa, const float* __restrict__ Wb,
    const float* __restrict__ ba, const float* __restrict__ bb,
    float* __restrict__ qt, float* __restrict__ kt,
    unsigned short* __restrict__ vtc)
{
    __shared__ unsigned       XsP[32][68];                 // [k][m] packed, 8.7 KB
    __shared__ unsigned short WsH[(MODE ? 128 : 64)][40];  // [cc][k]
    __shared__ unsigned short WsL[(MODE ? 128 : 64)][40];

    constexpr int CCT = MODE ? 8 : 4;       // col frags per wave
    const int m0 = blockIdx.x * 64;
    int b, s, cc0;
    const float* xptr;
    if (MODE == 0) { b = blockIdx.z; s = 0; cc0 = 0;
                     xptr = Xa + (size_t)b * C_ * N_; }
    else           { b = blockIdx.z & 3; s = blockIdx.z >> 2; cc0 = blockIdx.y * 128;
                     xptr = (s ? Xb : Xa) + (size_t)b * C_ * N_; }

    const int t = threadIdx.x;
    const int w = t >> 6, lane = t & 63, lr = lane & 15, ls = lane >> 4;

    f32x4 acc[CCT];
    #pragma unroll
    for (int i = 0; i < CCT; ++i) acc[i] = (f32x4){0.f, 0.f, 0.f, 0.f};

    const int skk = t >> 3, smo = (t & 7) * 8;       // X staging coords
    // W staging: MODE0: 64 rows, 8 k each; MODE1: 128 rows, 16 k each
    const int scc = MODE ? (t >> 1) : (t >> 2);
    const int sko = MODE ? ((t & 1) * 16) : ((t & 3) * 8);
    const float* wrow;
    if (MODE == 0) wrow = (scc < 32) ? (Wa + (size_t)scc * C_) : (Wb + (size_t)(scc - 32) * C_);
    else           wrow = Wa + (size_t)(cc0 + scc) * C_;

    for (int k0 = 0; k0 < C_; k0 += 32) {
        __syncthreads();
        {   // stage X tile 32k x 64m, packed
            const float* src = xptr + (size_t)(k0 + skk) * N_ + m0 + smo;
            f32x4 a = *(const f32x4*)src, c = *(const f32x4*)(src + 4);
            u32x4 p0, p1;
            p0[0]=packbf(a[0]); p0[1]=packbf(a[1]); p0[2]=packbf(a[2]); p0[3]=packbf(a[3]);
            p1[0]=packbf(c[0]); p1[1]=packbf(c[1]); p1[2]=packbf(c[2]); p1[3]=packbf(c[3]);
            *(u32x4*)&XsP[skk][smo]     = p0;
            *(u32x4*)&XsP[skk][smo + 4] = p1;
        }
        {   // stage W tile, split planes
            const int nk = MODE ? 16 : 8;
            #pragma unroll
            for (int q = 0; q < nk / 8; ++q) {
                f32x4 a = *(const f32x4*)(wrow + k0 + sko + q * 8);
                f32x4 c = *(const f32x4*)(wrow + k0 + sko + q * 8 + 4);
                us8 h, l; unsigned short hh, ll;
                splitbf(a[0],hh,ll); h[0]=hh; l[0]=ll;
                splitbf(a[1],hh,ll); h[1]=hh; l[1]=ll;
                splitbf(a[2],hh,ll); h[2]=hh; l[2]=ll;
                splitbf(a[3],hh,ll); h[3]=hh; l[3]=ll;
                splitbf(c[0],hh,ll); h[4]=hh; l[4]=ll;
                splitbf(c[1],hh,ll); h[5]=hh; l[5]=ll;
                splitbf(c[2],hh,ll); h[6]=hh; l[6]=ll;
                splitbf(c[3],hh,ll); h[7]=hh; l[7]=ll;
                *(us8*)&WsH[scc][sko + q * 8] = h;
                *(us8*)&WsL[scc][sko + q * 8] = l;
            }
        }
        __syncthreads();
        // A-frags: rows m = w*16+lr, k = ls*8+j (one b32 per elem, bank-clean)
        us8 ahu, alu;
        #pragma unroll
        for (int j = 0; j < 8; ++j) {
            unsigned v = XsP[ls*8 + j][w*16 + lr];
            ahu[j] = (unsigned short)v;
            alu[j] = (unsigned short)(v >> 16);
        }
        bf16x8 ah = asb(ahu), al = asb(alu);
        #pragma unroll
        for (int at = 0; at < CCT; ++at) {
            bf16x8 bh = asb(*(const us8*)&WsH[at*16 + lr][ls*8]);
            bf16x8 bl = asb(*(const us8*)&WsL[at*16 + lr][ls*8]);
            acc[at] = __builtin_amdgcn_mfma_f32_16x16x32_bf16(ah, bh, acc[at], 0, 0, 0);
            acc[at] = __builtin_amdgcn_mfma_f32_16x16x32_bf16(ah, bl, acc[at], 0, 0, 0);
            acc[at] = __builtin_amdgcn_mfma_f32_16x16x32_bf16(al, bh, acc[at], 0, 0, 0);
        }
    }

    const int mrow = m0 + w*16 + ls*4;
    if (MODE == 0) {
        #pragma unroll
        for (int at = 0; at < CCT; ++at) {
            const int cc = at*16 + lr;
            if (at < 2) {               // q half -> qt[b][n][cc]
                const float bia = ba[cc];
                #pragma unroll
                for (int r = 0; r < 4; ++r)
                    qt[((size_t)b * N_ + mrow + r) * C8_ + cc] = acc[at][r] + bia;
            } else {                    // k half -> kt[b][m][cc-32] (row-major)
                const float bia = bb[cc - 32];
                #pragma unroll
                for (int r = 0; r < 4; ++r)
                    kt[((size_t)b * N_ + mrow + r) * C8_ + (cc - 32)] = acc[at][r] + bia;
            }
        }
    } else {
        #pragma unroll
        for (int at = 0; at < CCT; ++at) {
            const int cc = cc0 + at*16 + lr;
            const float bia = ba[cc];
            us4 o;
            #pragma unroll
            for (int r = 0; r < 4; ++r) o[r] = f2bf(acc[at][r] + bia);
            *(us4*)&vtc[((size_t)b * 512 + s * 256 + cc) * N_ + mrow] = o;
        }
    }
}

// ---------------------------------------------------------------------------
// Fused PV.  Block = 32 q-rows x 512 cols, 512 thr / 8 waves, 64-m big tiles.
// E: all 8 waves, one 16x16 quadrant each (rt=w>>2, mt=w&3), K frags direct
// from global f32 (split in-reg, 3-term MFMA).  P -> Ps (stride-72, bank-
// clean).  PV: V frags direct from global bf16, reloaded in-place after use.
// Only LDS = Ps (4.6 KB) + Zpart.  2 barriers per 64-m tile.
// ---------------------------------------------------------------------------
__global__ __launch_bounds__(512, 4) void pv_k(
    const float* __restrict__ qt, const float* __restrict__ kt,
    const unsigned short* __restrict__ vtc,
    const float* __restrict__ xh1, const float* __restrict__ xl1,
    const float* __restrict__ g1, const float* __restrict__ g2,
    float* __restrict__ out)
{
    __shared__ unsigned short Ps[32][72];   // rows 144B (16B-mult); cols 0..63
    __shared__ float Zpart[4][32];

    // XCD-chunked: batch b on XCDs {2b, 2b+1}; K+V+qt of b stay L2-local.
    const int o      = blockIdx.x;
    const int xcd    = o & 7;
    const int b      = xcd >> 1;
    const int rowblk = (o >> 3) + (xcd & 1) * 64;
    const int n0     = rowblk * 32;

    const int t = threadIdx.x, w = t >> 6, lane = t & 63;
    const int lr = lane & 15, ls = lane >> 4;
    const int wn = w * 64;                  // PV col base (0..448)
    const int rt = w >> 2;                  // E row-half
    const int mt = w & 3;                   // E m-quarter

    // --- Q frag (rows rt*16+lr), split hi/lo, loop-invariant ---
    bf16x8 qh, ql;
    {
        const float* qrow = qt + ((size_t)b * N_ + n0 + rt*16 + lr) * C8_ + ls*8;
        f32x4 q0 = *(const f32x4*)qrow, q1 = *(const f32x4*)(qrow + 4);
        us8 hu, lu; unsigned short hh, ll;
        splitbf(q0[0],hh,ll); hu[0]=hh; lu[0]=ll;
        splitbf(q0[1],hh,ll); hu[1]=hh; lu[1]=ll;
        splitbf(q0[2],hh,ll); hu[2]=hh; lu[2]=ll;
        splitbf(q0[3],hh,ll); hu[3]=hh; lu[3]=ll;
        splitbf(q1[0],hh,ll); hu[4]=hh; lu[4]=ll;
        splitbf(q1[1],hh,ll); hu[5]=hh; lu[5]=ll;
        splitbf(q1[2],hh,ll); hu[6]=hh; lu[6]=ll;
        splitbf(q1[3],hh,ll); hu[7]=hh; lu[7]=ll;
        qh = asb(hu); ql = asb(lu);
    }

    f32x4 acc[2][4];
    #pragma unroll
    for (int i = 0; i < 2; ++i)
        #pragma unroll
        for (int j = 0; j < 4; ++j) acc[i][j] = (f32x4){0.f, 0.f, 0.f, 0.f};
    float zreg[4] = {0.f, 0.f, 0.f, 0.f};

    // --- direct-global fragment pointers ---
    const float* kp = kt + ((size_t)b * N_ + mt*16 + lr) * C8_ + ls*8;   // E B-frag
    const unsigned short* vbase = vtc + (size_t)b * 512 * N_;
    const unsigned short* vp[4];
    #pragma unroll
    for (int fj = 0; fj < 4; ++fj)
        vp[fj] = vbase + (size_t)(wn + fj*16 + lr) * N_ + ls*8;

    // --- prologue: K(0), V(0) into regs ---
    f32x4 kc0 = *(const f32x4*)kp, kc1 = *(const f32x4*)(kp + 4);
    us8 v[4][2];
    #pragma unroll
    for (int fj = 0; fj < 4; ++fj) {
        v[fj][0] = *(const us8*)(vp[fj]);
        v[fj][1] = *(const us8*)(vp[fj] + 32);
    }

    for (int tile = 0; tile < NT64_; ++tile) {
        // ---- phase A: E quadrant (split-bf16 3-term) -> exp -> Ps ----
        {
            us8 khu, klu; unsigned short hh, ll;
            splitbf(kc0[0],hh,ll); khu[0]=hh; klu[0]=ll;
            splitbf(kc0[1],hh,ll); khu[1]=hh; klu[1]=ll;
            splitbf(kc0[2],hh,ll); khu[2]=hh; klu[2]=ll;
            splitbf(kc0[3],hh,ll); khu[3]=hh; klu[3]=ll;
            splitbf(kc1[0],hh,ll); khu[4]=hh; klu[4]=ll;
            splitbf(kc1[1],hh,ll); khu[5]=hh; klu[5]=ll;
            splitbf(kc1[2],hh,ll); khu[6]=hh; klu[6]=ll;
            splitbf(kc1[3],hh,ll); khu[7]=hh; klu[7]=ll;
            bf16x8 kh = asb(khu), kl = asb(klu);
            f32x4 ea = (f32x4){0.f, 0.f, 0.f, 0.f};
            ea = __builtin_amdgcn_mfma_f32_16x16x32_bf16(qh, kh, ea, 0, 0, 0);
            ea = __builtin_amdgcn_mfma_f32_16x16x32_bf16(qh, kl, ea, 0, 0, 0);
            ea = __builtin_amdgcn_mfma_f32_16x16x32_bf16(ql, kh, ea, 0, 0, 0);
            if (tile + 1 < NT64_) {             // prefetch K(tile+1)
                kc0 = *(const f32x4*)(kp + (size_t)(tile + 1) * 64 * C8_);
                kc1 = *(const f32x4*)(kp + (size_t)(tile + 1) * 64 * C8_ + 4);
            }
            #pragma unroll
            for (int r = 0; r < 4; ++r) {
                float pe = __expf(ea[r] - 20.f);
                zreg[r] += pe;
                Ps[rt*16 + ls*4 + r][mt*16 + lr] = f2bf(pe);
            }
        }
        __syncthreads();
        // ---- phase B: PV MFMA, then reload V regs for tile+1 in-place ----
        {
            bf16x8 pa00 = asb(*(const us8*)&Ps[lr][ls*8]);
            bf16x8 pa01 = asb(*(const us8*)&Ps[lr][32 + ls*8]);
            bf16x8 pa10 = asb(*(const us8*)&Ps[16 + lr][ls*8]);
            bf16x8 pa11 = asb(*(const us8*)&Ps[16 + lr][32 + ls*8]);
            #pragma unroll
            for (int fj = 0; fj < 4; ++fj) {
                acc[0][fj] = __builtin_amdgcn_mfma_f32_16x16x32_bf16(pa00, asb(v[fj][0]), acc[0][fj], 0,0,0);
                acc[1][fj] = __builtin_amdgcn_mfma_f32_16x16x32_bf16(pa10, asb(v[fj][0]), acc[1][fj], 0,0,0);
                acc[0][fj] = __builtin_amdgcn_mfma_f32_16x16x32_bf16(pa01, asb(v[fj][1]), acc[0][fj], 0,0,0);
                acc[1][fj] = __builtin_amdgcn_mfma_f32_16x16x32_bf16(pa11, asb(v[fj][1]), acc[1][fj], 0,0,0);
            }
            if (tile + 1 < NT64_) {             // V(tile+1) into same regs
                const int mo = (tile + 1) * 64;
                #pragma unroll
                for (int fj = 0; fj < 4; ++fj) {
                    v[fj][0] = *(const us8*)(vp[fj] + mo);
                    v[fj][1] = *(const us8*)(vp[fj] + mo + 32);
                }
            }
        }
        __syncthreads();
    }

    // ---- Z finalize: reduce over lr, combine 4 m-quarters ----
    #pragma unroll
    for (int r = 0; r < 4; ++r) {
        float z = zreg[r];
        z += __shfl_xor(z, 1, 16); z += __shfl_xor(z, 2, 16);
        z += __shfl_xor(z, 4, 16); z += __shfl_xor(z, 8, 16);
        if (lr == 0) Zpart[mt][rt*16 + ls*4 + r] = z;
    }
    __syncthreads();

    float rzf[2][4];
    #pragma unroll
    for (int rh = 0; rh < 2; ++rh)
        #pragma unroll
        for (int r = 0; r < 4; ++r) {
            const int row = rh*16 + ls*4 + r;
            rzf[rh][r] = 1.f / (Zpart[0][row] + Zpart[1][row] + Zpart[2][row] + Zpart[3][row]);
        }

    const float g1v = g1[0], g2v = g2[0];
    #pragma unroll
    for (int rh = 0; rh < 2; ++rh) {
        const int nb = rh*16 + ls*4;
        #pragma unroll
        for (int fj = 0; fj < 4; ++fj) {
            const int cc = wn + fj*16 + lr;          // 0..511
            const int st = cc >> 8;                  // 0 = h, 1 = l
            const float  gv = st ? g2v : g1v;
            const float* xg = st ? xl1 : xh1;
            float* og = out + (st ? (size_t)B_ * C_ * N_ : (size_t)0);
            const size_t base = ((size_t)b * C_ + (cc & 255)) * N_ + n0 + nb;
            f32x4 xv = *(const f32x4*)(xg + base);
            f32x4 ov;
            #pragma unroll
            for (int r = 0; r < 4; ++r)
                ov[r] = xv[r] * (gv * (acc[rh][fj][r] * rzf[rh][r]));
            *(f32x4*)(og + base) = ov;
        }
    }
}

// ---------------------------------------------------------------------------
extern "C" void kernel_launch(void* const* d_in, const int* in_sizes, int n_in,
                              void* d_out, int out_size, void* d_ws, size_t ws_size,
                              hipStream_t stream)
{
    const float* x   = (const float*)d_in[0];
    const float* xh1 = (const float*)d_in[1];
    const float* xl1 = (const float*)d_in[2];
    const float* Wq  = (const float*)d_in[3];
    const float* bq  = (const float*)d_in[4];
    const float* Wk  = (const float*)d_in[5];
    const float* bk  = (const float*)d_in[6];
    const float* Wv  = (const float*)d_in[7];
    const float* bv  = (const float*)d_in[8];
    const float* g1  = (const float*)d_in[9];
    const float* g2  = (const float*)d_in[10];
    float* out = (float*)d_out;

    // Workspace (~20 MB): qt 2MB | kt 2MB | vtc 16MB
    char* pws = (char*)d_ws;
    float* qt = (float*)pws;                  pws += (size_t)B_ * N_ * C8_ * 4;
    float* kt = (float*)pws;                  pws += (size_t)B_ * N_ * C8_ * 4;
    unsigned short* vtc = (unsigned short*)pws;

    proj_k<0><<<dim3(N_ / 64, 1, B_),     256, 0, stream>>>(
        x, nullptr, Wq, Wk, bq, bk, qt, kt, nullptr);
    proj_k<1><<<dim3(N_ / 64, 2, B_ * 2), 256, 0, stream>>>(
        xh1, xl1, Wv, nullptr, bv, nullptr, nullptr, nullptr, vtc);
    pv_k<<<dim3(512), 512, 0, stream>>>(qt, kt, vtc, xh1, xl1, g1, g2, out);
}